// Round 1
// 307.652 us; speedup vs baseline: 1.0096x; 1.0096x over previous
//
#include <hip/hip_runtime.h>
#include <hip/hip_bf16.h>
#include <stdint.h>

// ---------------------------------------------------------------------------
// CapsuleLayerSemantic: LN -> per-adapter (W1,relu,W2) -> capsule squash over A
// B=16 S=2048 NX=1024 A=20 H=50 O=3.  M = 32768 tokens.
// R8: GEMM ported to the 256x256 8-phase schedule (T2 swizzle + T3/T4 counted
//     vmcnt + T5 setprio): BK=64, 512 thr (8 waves 2x4), 128KB LDS dbuf,
//     4 phases/K-tile, vmcnt(4) once per window (never 0 in main loop).
//     BN=256 cuts boundary-split adapters 7 -> {5,10,15} (fewer atomics,
//     48 zero-blocks instead of 112). ln/squash unchanged.
// ---------------------------------------------------------------------------

typedef _Float16 h8 __attribute__((ext_vector_type(8)));
typedef float f4 __attribute__((ext_vector_type(4)));
typedef __attribute__((address_space(1))) void gvoid;
typedef __attribute__((address_space(3))) void lvoid;

__device__ __forceinline__ void cp16(const void* g, void* l) {
  __builtin_amdgcn_global_load_lds((gvoid*)g, (lvoid*)l, 16, 0, 0);
}

// ---------------- kernel 1: layernorm + fp16 cast (one wave per token) ------
__global__ __launch_bounds__(256) void ln_kernel(const float* __restrict__ x,
                                                 _Float16* __restrict__ xn) {
  const int t = threadIdx.x, w = t >> 6, l = t & 63;
  const int tok = blockIdx.x * 4 + w;
  const float4* xr = (const float4*)(x + (size_t)tok * 1024);
  float4 v0 = xr[l], v1 = xr[64 + l], v2 = xr[128 + l], v3 = xr[192 + l];
  float s1 = (v0.x + v0.y + v0.z + v0.w) + (v1.x + v1.y + v1.z + v1.w) +
             (v2.x + v2.y + v2.z + v2.w) + (v3.x + v3.y + v3.z + v3.w);
  float s2 = v0.x * v0.x + v0.y * v0.y + v0.z * v0.z + v0.w * v0.w;
  s2 += v1.x * v1.x + v1.y * v1.y + v1.z * v1.z + v1.w * v1.w;
  s2 += v2.x * v2.x + v2.y * v2.y + v2.z * v2.z + v2.w * v2.w;
  s2 += v3.x * v3.x + v3.y * v3.y + v3.z * v3.z + v3.w * v3.w;
#pragma unroll
  for (int m = 32; m > 0; m >>= 1) {
    s1 += __shfl_xor(s1, m);
    s2 += __shfl_xor(s2, m);
  }
  const float mu = s1 * 0.0009765625f;
  const float var = s2 * 0.0009765625f - mu * mu;
  const float inv = rsqrtf(var + 1e-5f);
  uint2* xw = (uint2*)(xn + (size_t)tok * 1024);
  union { _Float16 h[4]; uint2 u; } q;
#define CVT_STORE(V, OFF)                                   \
  q.h[0] = (_Float16)((V.x - mu) * inv);                    \
  q.h[1] = (_Float16)((V.y - mu) * inv);                    \
  q.h[2] = (_Float16)((V.z - mu) * inv);                    \
  q.h[3] = (_Float16)((V.w - mu) * inv);                    \
  xw[(OFF) + l] = q.u;
  CVT_STORE(v0, 0)
  CVT_STORE(v1, 64)
  CVT_STORE(v2, 128)
  CVT_STORE(v3, 192)
#undef CVT_STORE
}

// ---------------- kernel 2: prep + out-slice zeroing ------------------------
// blocks [0,320): (a = b/16, ky = b%16): W1*ln_g transpose -> packed wB fp16,
//   exact off partial for this k-chunk -> offpart[ky][a*50+h].
//   a==0 blocks also zero wB pad rows 1000..1023 for their k-chunk.
// blocks [320,368): zero the out-slices of the 3 boundary-split adapters
//   {5,10,15} (BN=256 in the gemm) which receive atomicAdd in the epilogue.
__global__ __launch_bounds__(256) void prep_w(const float* __restrict__ ln_g,
                                              const float* __restrict__ ln_b,
                                              const float* __restrict__ W1,
                                              _Float16* __restrict__ wB,
                                              float* __restrict__ offpart,
                                              float* __restrict__ out) {
  const int t = threadIdx.x;
  if (blockIdx.x >= 320) {
    static const int sa[3] = {5, 10, 15};
    const int idx = blockIdx.x - 320;        // 0..47
    const int ai = idx >> 4, bi = idx & 15;  // adapter-slot, batch
    float4* dst = (float4*)(out + ((size_t)(bi * 20 + sa[ai])) * 6144);
    const float4 z4 = {0.f, 0.f, 0.f, 0.f};
    for (int i = t; i < 1536; i += 256) dst[i] = z4;
    return;
  }
  const int a = blockIdx.x >> 4, k0 = (blockIdx.x & 15) * 64;
  __shared__ float tw[3200];  // W1[a][k0..k0+64][0..50]
  __shared__ float gg[64], bb[64], red[256];
  const float* src = W1 + (size_t)(a * 1024 + k0) * 50;
  for (int i = t; i < 3200; i += 256) tw[i] = src[i];
  if (t < 64) gg[t] = ln_g[a * 1024 + k0 + t];
  else if (t < 128) bb[t - 64] = ln_b[a * 1024 + k0 + (t - 64)];
  __syncthreads();
  const int h = t & 63, q = t >> 6;
  float po = 0.f;
  if (h < 50) {
#pragma unroll
    for (int half = 0; half < 2; ++half) {
      union { _Float16 hh[8]; uint4 u; } pk;
#pragma unroll
      for (int j = 0; j < 8; ++j) {
        const int k = q * 16 + half * 8 + j;
        const float wv = tw[k * 50 + h];
        pk.hh[j] = (_Float16)(gg[k] * wv);
        po += bb[k] * wv;
      }
      *(uint4*)(wB + (size_t)(a * 50 + h) * 1024 + k0 + q * 16 + half * 8) =
          pk.u;
    }
  }
  red[t] = po;
  __syncthreads();
  if (t < 50)
    offpart[(blockIdx.x & 15) * 1024 + a * 50 + t] =
        red[t] + red[64 + t] + red[128 + t] + red[192 + t];
  if (a == 0 && t < 192) {  // zero wB pad rows 1000..1023 for this k-chunk
    const uint4 z = {0, 0, 0, 0};
    *(uint4*)(wB + (size_t)(1000 + (t >> 3)) * 1024 + k0 + (t & 7) * 8) = z;
  }
}

// ---------------- kernel 3: 256x256 8-phase GEMM + fused epilogue -----------
// Grid 512 (mb 0..127 x nb 0..3), XCD-swizzled: xcd=g&7, mb=xcd*16+(i>>2),
// nb=i&3 -> each XCD reuses one 512KB A-tile across 4 nb via its L2; wB (2MB)
// stays L2-resident. 512 threads = 8 waves (wr=w>>2 in [0,2), wc=w&3 in [0,4)),
// per-wave C = 128x64 (mt 0..7, nt 0..3). BK=64, mfma 16x16x32 f16.
// LDS: 2 dbuf x 64KB; dbuf c at c*65536: A half h at h*16384, B at 32768+h*16384.
// 16B-slot XOR swizzle (slot ^ row&7), staged via pre-swizzled global source.
// Window per K-tile kt (4 phases, 2 raw barriers each, vmcnt counted):
//  P1: rd afA(8)+bf01(4); stage B halves of kt+1 -> other buf; bar;lgk0;Q0;bar
//  P2: rd bf23(4); bar;lgk0;Q1;bar
//  P3: rd afB(8); bar;lgk0;Q2;bar
//  P4: stage A halves of kt+2 -> current buf (reads done at P3 bar);
//      s_waitcnt vmcnt(4) [= kt+1 fully landed]; bar; Q3; bar
__global__ __launch_bounds__(512, 2) void gemm_kernel(
    const _Float16* __restrict__ xn, const _Float16* __restrict__ wB,
    const float* __restrict__ offpart, const float* __restrict__ b1,
    const float* __restrict__ W2, float* __restrict__ out) {
  __shared__ __align__(16) char smem[134672];
  // [0,131072) main dbuf | epilogue reuse: hm[64][260] f32 = 66560
  // [131072,134672) w2s: 900 f32 (W2 for adapters a0..a0+5)
  const int g = blockIdx.x;
  const int xcd = g & 7, i0 = g >> 3;
  const int nb = i0 & 3;
  const int mb = xcd * 16 + (i0 >> 2);
  const int t = threadIdx.x, w = t >> 6, l = t & 63;
  const int wr = w >> 2, wc = w & 3;

  // W2 staging (before any global_load_lds so compiler waits don't interleave)
  float* w2s = (float*)(smem + 131072);
  const int a0 = (nb * 256) / 50;
  for (int i = t; i < 900; i += 512) {
    const int j = i / 150, a = a0 + j;
    w2s[i] = (a < 20) ? W2[a * 150 + (i - j * 150)] : 0.f;
  }

  // staging: thread t covers row (t>>3) (+64 per j), phys 16B slot t&7 holding
  // logical slot (t&7)^(row&7); LDS dest is wave-uniform base + lane*16.
  const int sr = t >> 3;
  const int sl = (t & 7) ^ (sr & 7);
  const _Float16* gA = xn + (size_t)(mb * 256 + sr) * 1024 + sl * 8;
  const _Float16* gB = wB + (size_t)(nb * 256 + sr) * 1024 + sl * 8;
  const int woff = w * 1024;

  // LDS read bases (identical fragment math to proven R7, per-half)
  const int kq = l >> 4, xr = l & 7;
  const char* pA0 = smem + wr * 16384 + (l & 15) * 128;
  const char* pB0 =
      smem + 32768 + (wc >> 1) * 16384 + ((wc & 1) * 64 + (l & 15)) * 128;

  f4 acc[8][4];
  {
    f4 z = {0.f, 0.f, 0.f, 0.f};
#pragma unroll
    for (int mt = 0; mt < 8; ++mt)
#pragma unroll
      for (int nt = 0; nt < 4; ++nt) acc[mt][nt] = z;
  }

  // ---- prologue: kt0 (A+B) -> buf0, kt1 A halves -> buf1 : 12 loads -------
  cp16(gA, smem + woff);
  cp16(gA + (size_t)64 * 1024, smem + 8192 + woff);
  cp16(gA + (size_t)128 * 1024, smem + 16384 + woff);
  cp16(gA + (size_t)192 * 1024, smem + 24576 + woff);
  cp16(gB, smem + 32768 + woff);
  cp16(gB + (size_t)64 * 1024, smem + 40960 + woff);
  cp16(gB + (size_t)128 * 1024, smem + 49152 + woff);
  cp16(gB + (size_t)192 * 1024, smem + 57344 + woff);
  cp16(gA + 64, smem + 65536 + woff);
  cp16(gA + (size_t)64 * 1024 + 64, smem + 65536 + 8192 + woff);
  cp16(gA + (size_t)128 * 1024 + 64, smem + 65536 + 16384 + woff);
  cp16(gA + (size_t)192 * 1024 + 64, smem + 65536 + 24576 + woff);
  asm volatile("s_waitcnt vmcnt(4)" ::: "memory");
  __builtin_amdgcn_s_barrier();

#pragma unroll 2
  for (int kt = 0; kt < 16; ++kt) {
    const int cb = (kt & 1) << 16;
    const int ob = cb ^ 65536;
    h8 afA[4][2], afB[4][2], bf[4][2];
#define RDA(mt, ks) \
  (*(const h8*)(pA0 + cb + (mt)*2048 + ((((ks)*4 + kq) ^ xr) << 4)))
#define RDB(nt, ks) \
  (*(const h8*)(pB0 + cb + (nt)*2048 + ((((ks)*4 + kq) ^ xr) << 4)))
    // ---------------- P1 ----------------
#pragma unroll
    for (int mt = 0; mt < 4; ++mt) {
      afA[mt][0] = RDA(mt, 0);
      afA[mt][1] = RDA(mt, 1);
    }
#pragma unroll
    for (int nt = 0; nt < 2; ++nt) {
      bf[nt][0] = RDB(nt, 0);
      bf[nt][1] = RDB(nt, 1);
    }
    if (kt < 15) {  // stage B halves of kt+1 -> other buf
      cp16(gB + (kt + 1) * 64, smem + ob + 32768 + woff);
      cp16(gB + (size_t)64 * 1024 + (kt + 1) * 64, smem + ob + 40960 + woff);
      cp16(gB + (size_t)128 * 1024 + (kt + 1) * 64, smem + ob + 49152 + woff);
      cp16(gB + (size_t)192 * 1024 + (kt + 1) * 64, smem + ob + 57344 + woff);
    }
    __builtin_amdgcn_s_barrier();
    asm volatile("s_waitcnt lgkmcnt(0)" ::: "memory");
    __builtin_amdgcn_s_setprio(1);
#pragma unroll
    for (int mt = 0; mt < 4; ++mt)
#pragma unroll
      for (int nt = 0; nt < 2; ++nt)
#pragma unroll
        for (int ks = 0; ks < 2; ++ks)
          acc[mt][nt] = __builtin_amdgcn_mfma_f32_16x16x32_f16(
              afA[mt][ks], bf[nt][ks], acc[mt][nt], 0, 0, 0);
    __builtin_amdgcn_s_setprio(0);
    __builtin_amdgcn_s_barrier();
    // ---------------- P2 ----------------
#pragma unroll
    for (int nt = 2; nt < 4; ++nt) {
      bf[nt][0] = RDB(nt, 0);
      bf[nt][1] = RDB(nt, 1);
    }
    __builtin_amdgcn_s_barrier();
    asm volatile("s_waitcnt lgkmcnt(0)" ::: "memory");
    __builtin_amdgcn_s_setprio(1);
#pragma unroll
    for (int mt = 0; mt < 4; ++mt)
#pragma unroll
      for (int nt = 2; nt < 4; ++nt)
#pragma unroll
        for (int ks = 0; ks < 2; ++ks)
          acc[mt][nt] = __builtin_amdgcn_mfma_f32_16x16x32_f16(
              afA[mt][ks], bf[nt][ks], acc[mt][nt], 0, 0, 0);
    __builtin_amdgcn_s_setprio(0);
    __builtin_amdgcn_s_barrier();
    // ---------------- P3 ----------------
#pragma unroll
    for (int mt = 0; mt < 4; ++mt) {
      afB[mt][0] = RDA(4 + mt, 0);
      afB[mt][1] = RDA(4 + mt, 1);
    }
    __builtin_amdgcn_s_barrier();
    asm volatile("s_waitcnt lgkmcnt(0)" ::: "memory");
    __builtin_amdgcn_s_setprio(1);
#pragma unroll
    for (int mt = 0; mt < 4; ++mt)
#pragma unroll
      for (int nt = 0; nt < 2; ++nt)
#pragma unroll
        for (int ks = 0; ks < 2; ++ks)
          acc[4 + mt][nt] = __builtin_amdgcn_mfma_f32_16x16x32_f16(
              afB[mt][ks], bf[nt][ks], acc[4 + mt][nt], 0, 0, 0);
    __builtin_amdgcn_s_setprio(0);
    __builtin_amdgcn_s_barrier();
    // ---------------- P4 ----------------
    if (kt < 14) {  // stage A halves of kt+2 -> current buf (reads done)
      cp16(gA + (kt + 2) * 64, smem + cb + woff);
      cp16(gA + (size_t)64 * 1024 + (kt + 2) * 64, smem + cb + 8192 + woff);
      cp16(gA + (size_t)128 * 1024 + (kt + 2) * 64, smem + cb + 16384 + woff);
      cp16(gA + (size_t)192 * 1024 + (kt + 2) * 64, smem + cb + 24576 + woff);
      asm volatile("s_waitcnt vmcnt(4)" ::: "memory");
    } else {
      asm volatile("s_waitcnt vmcnt(0)" ::: "memory");
    }
    __builtin_amdgcn_s_barrier();
    __builtin_amdgcn_s_setprio(1);
#pragma unroll
    for (int mt = 0; mt < 4; ++mt)
#pragma unroll
      for (int nt = 2; nt < 4; ++nt)
#pragma unroll
        for (int ks = 0; ks < 2; ++ks)
          acc[4 + mt][nt] = __builtin_amdgcn_mfma_f32_16x16x32_f16(
              afB[mt][ks], bf[nt][ks], acc[4 + mt][nt], 0, 0, 0);
    __builtin_amdgcn_s_setprio(0);
    __builtin_amdgcn_s_barrier();
#undef RDA
#undef RDB
  }
  __syncthreads();  // full drain before LDS reuse

  // off_total[nt] = b1[n] + sum_{c<16} offpart[c][n]  (4KB+64KB, L2-hot)
  float offt[4];
  int ncols[4];
#pragma unroll
  for (int nt = 0; nt < 4; ++nt) {
    ncols[nt] = nb * 256 + wc * 64 + nt * 16 + (l & 15);
    offt[nt] = (ncols[nt] < 1000) ? b1[ncols[nt]] : 0.f;
  }
#pragma unroll
  for (int c = 0; c < 16; ++c)
#pragma unroll
    for (int nt = 0; nt < 4; ++nt) offt[nt] += offpart[c * 1024 + ncols[nt]];

  // per-thread dot assignment: 64 tokens x 8 adapter slots (6 active)
  const int ml = t >> 3, j = t & 7;
  const int a = a0 + j;
  const int c0 = nb * 256;
  int cs = a * 50, ce = cs + 50;
  if (cs < c0) cs = c0;
  if (ce > c0 + 256) ce = c0 + 256;
  const bool act = (j < 6) && (a < 20) && (cs < ce);
  const int lo = cs - c0;
  const int len = act ? (ce - cs) : 0;
  const int h0 = cs - a * 50;
  const float* wrow = w2s + j * 150 + h0 * 3;

  float* hm = (float*)smem;  // [64][260]
#pragma unroll
  for (int p = 0; p < 4; ++p) {
    if (p) __syncthreads();
    if (wr == (p >> 1)) {
      const int mtb = (p & 1) * 4;
#pragma unroll
      for (int q = 0; q < 4; ++q)
#pragma unroll
        for (int nt = 0; nt < 4; ++nt)
#pragma unroll
          for (int r = 0; r < 4; ++r)
            hm[(q * 16 + kq * 4 + r) * 260 + (wc * 64 + nt * 16 + (l & 15))] =
                fmaxf(acc[mtb + q][nt][r] + offt[nt], 0.f);
    }
    __syncthreads();
    if (act) {
      const float* hr = hm + ml * 260 + lo;
      float o0 = 0.f, o1 = 0.f, o2 = 0.f;
      for (int i = 0; i < len; ++i) {
        const float hv = hr[i];
        o0 += hv * wrow[i * 3 + 0];
        o1 += hv * wrow[i * 3 + 1];
        o2 += hv * wrow[i * 3 + 2];
      }
      const int tok = mb * 256 + p * 64 + ml;
      const int b = tok >> 11, s = tok & 2047;
      float* op = out + ((size_t)(b * 20 + a) * 2048 + (size_t)s) * 3;
      if (len == 50) {  // adapter fully inside this nb block: direct store
        op[0] = o0; op[1] = o1; op[2] = o2;
      } else {          // boundary-split adapter: slice was pre-zeroed
        atomicAdd(op + 0, o0);
        atomicAdd(op + 1, o1);
        atomicAdd(op + 2, o2);
      }
    }
  }
}

// ---------------- kernel 4: +b2, capsule squash over A, in place ------------
__global__ __launch_bounds__(256) void squash_kernel(
    float* __restrict__ out, const float* __restrict__ b2) {
  const int idx = blockIdx.x * 256 + threadIdx.x;  // 0 .. 16*6144-1
  const int b = idx / 6144;
  const int rem = idx - b * 6144;
  const int oi = rem % 3;
  float v[20];
  float sq = 0.f;
#pragma unroll
  for (int a = 0; a < 20; ++a) {
    v[a] = out[((size_t)(b * 20 + a)) * 6144 + rem] + b2[a * 3 + oi];
    sq += v[a] * v[a];
  }
  const float f = sqrtf(sq) / (1.f + sq);  // (sq/(1+sq))*rsqrt(sq), safe at 0
#pragma unroll
  for (int a = 0; a < 20; ++a)
    out[((size_t)(b * 20 + a)) * 6144 + rem] = v[a] * f;
}

// ---------------------------------------------------------------------------
extern "C" void kernel_launch(void* const* d_in, const int* in_sizes, int n_in,
                              void* d_out, int out_size, void* d_ws,
                              size_t ws_size, hipStream_t stream) {
  const float* x    = (const float*)d_in[0];  // [16,2048,1024]
  const float* ln_g = (const float*)d_in[1];  // [20,1024]
  const float* ln_b = (const float*)d_in[2];  // [20,1024]
  const float* W1   = (const float*)d_in[3];  // [20,1024,50]
  const float* b1   = (const float*)d_in[4];  // [20,50]
  const float* W2   = (const float*)d_in[5];  // [20,50,3]
  const float* b2   = (const float*)d_in[6];  // [20,3]
  float* out = (float*)d_out;                 // [16,20,6144]

  char* ws = (char*)d_ws;
  float* offpart = (float*)ws;                        // [16][1024] f32 (64KB)
  _Float16* wBw  = (_Float16*)(ws + 65536);           // 1024*1024 fp16 (2MB)
  _Float16* xnw  = (_Float16*)(ws + 65536 + 2097152); // 32768*1024 fp16 (67MB)

  prep_w<<<368, 256, 0, stream>>>(ln_g, ln_b, W1, wBw, offpart, out);
  ln_kernel<<<8192, 256, 0, stream>>>(x, xnw);
  gemm_kernel<<<512, 512, 0, stream>>>(xnw, wBw, offpart, b1, W2, out);
  squash_kernel<<<384, 256, 0, stream>>>(out, b2);
}